// Round 1
// baseline (257.408 us; speedup 1.0000x reference)
//
#include <hip/hip_runtime.h>

#define L_DIM 128
#define B_DIM 128
#define D_DIM 1024
#define A_DIM 1024
#define H_DIM 2048
#define KSPLIT 16

// 2*log2(e): tanh(x) = 1 - 2/(exp2(x*KC)+1)
#define KC 2.8853900817779268f
#define LOG2E 1.4426950408889634f

// ---------------------------------------------------------------------------
// K1a: split-K GEMM partials. proj_part[kc][b][a] = sum_{d in chunk kc}
//      s_tm1[b][d] * W_sa[a][d].  No atomics: each (a-tile, b-tile, kc)
//      block owns its 64x64 tile of slice kc.  Partials land in L2 (8 MB).
// ---------------------------------------------------------------------------
__global__ __launch_bounds__(256) void k1_gemm_part(const float* __restrict__ s_tm1,
                                                    const float* __restrict__ W_sa,
                                                    float* __restrict__ proj_part) {
    __shared__ float sWT[64][68];  // [d][a], +4 pad
    __shared__ float sST[64][68];  // [d][b]
    const int a0 = blockIdx.x * 64;
    const int b0 = blockIdx.y * 64;
    const int kc = blockIdx.z;
    const int k0 = kc * 64;
    const int t  = threadIdx.x;

    {
        const int c = (t & 15) * 4;   // d offset within chunk
        const int r = t >> 4;
#pragma unroll
        for (int p = 0; p < 4; ++p) {
            const int row = r + p * 16;
            float4 w4 = *(const float4*)(W_sa + (size_t)(a0 + row) * D_DIM + k0 + c);
            sWT[c + 0][row] = w4.x; sWT[c + 1][row] = w4.y;
            sWT[c + 2][row] = w4.z; sWT[c + 3][row] = w4.w;
            float4 s4 = *(const float4*)(s_tm1 + (size_t)(b0 + row) * D_DIM + k0 + c);
            sST[c + 0][row] = s4.x; sST[c + 1][row] = s4.y;
            sST[c + 2][row] = s4.z; sST[c + 3][row] = s4.w;
        }
    }
    __syncthreads();

    const int tx = t & 15;   // a quad
    const int ty = t >> 4;   // b quad
    float acc[4][4] = {};
#pragma unroll 4
    for (int d = 0; d < 64; ++d) {
        float4 av = *(const float4*)&sWT[d][tx * 4];
        float4 bv = *(const float4*)&sST[d][ty * 4];
        float a_[4] = {av.x, av.y, av.z, av.w};
        float b_[4] = {bv.x, bv.y, bv.z, bv.w};
#pragma unroll
        for (int j = 0; j < 4; ++j)
#pragma unroll
            for (int i = 0; i < 4; ++i)
                acc[j][i] += a_[i] * b_[j];
    }

    float* base = proj_part + (size_t)kc * B_DIM * A_DIM;
#pragma unroll
    for (int j = 0; j < 4; ++j)
#pragma unroll
        for (int i = 0; i < 4; ++i)
            base[(size_t)(b0 + ty * 4 + j) * A_DIM + a0 + tx * 4 + i] = acc[j][i];
}

// ---------------------------------------------------------------------------
// K1b: proj2 = (sum over 16 K-slices + b_sa) * 2*log2(e).
// Block 0 additionally precomputes c0 = (sum(w_a1) + b_a1) * log2(e),
// used by K2's factored logit:  logit = sum_w - 2 * sum_a w_a / (e^{2x_a}+1).
// ---------------------------------------------------------------------------
__global__ __launch_bounds__(256) void k1_reduce(const float* __restrict__ proj_part,
                                                 const float* __restrict__ b_sa,
                                                 const float* __restrict__ w_a1,
                                                 const float* __restrict__ b_a1,
                                                 float* __restrict__ proj2,
                                                 float* __restrict__ c0) {
    __shared__ float sw[4];
    const size_t i4 = (size_t)blockIdx.x * 256 + threadIdx.x;  // float4 index
    const float4* pp = (const float4*)proj_part;
    float4 acc = pp[i4];
#pragma unroll
    for (int kc = 1; kc < KSPLIT; ++kc) {
        float4 v = pp[(size_t)kc * (B_DIM * A_DIM / 4) + i4];
        acc.x += v.x; acc.y += v.y; acc.z += v.z; acc.w += v.w;
    }
    const int a4 = (int)(i4 & (A_DIM / 4 - 1));
    float4 bs = ((const float4*)b_sa)[a4];
    float4 o;
    o.x = (acc.x + bs.x) * KC; o.y = (acc.y + bs.y) * KC;
    o.z = (acc.z + bs.z) * KC; o.w = (acc.w + bs.w) * KC;
    ((float4*)proj2)[i4] = o;

    if (blockIdx.x == 0) {
        float4 w4 = ((const float4*)w_a1)[threadIdx.x];  // 256*4 = 1024 = A
        float s = w4.x + w4.y + w4.z + w4.w;
#pragma unroll
        for (int off = 32; off > 0; off >>= 1)
            s += __shfl_down(s, off);
        if ((threadIdx.x & 63) == 0) sw[threadIdx.x >> 6] = s;
        __syncthreads();
        if (threadIdx.x == 0)
            c0[0] = (sw[0] + sw[1] + sw[2] + sw[3] + b_a1[0]) * LOG2E;
    }
}

// ---------------------------------------------------------------------------
// K2: e_raw[l][b] = exp2(c0 - KC * sum_a w_a1[a] / (exp2(fma(uh, KC, proj2))+1))
//     * mask[l][b].   One wave per (l,b).  Inner: fma+exp2+add+rcp+fma.
// ---------------------------------------------------------------------------
__global__ __launch_bounds__(256) void k2_logits(const float* __restrict__ uh,
                                                 const float* __restrict__ proj2,
                                                 const float* __restrict__ w_a1,
                                                 const float* __restrict__ c0p,
                                                 const float* __restrict__ mask,
                                                 float* __restrict__ e_raw) {
    const int wave = threadIdx.x >> 6;
    const int lane = threadIdx.x & 63;
    const int flat = blockIdx.x * 4 + wave;        // l*B + b
    const int b    = flat & (B_DIM - 1);

    const float* up = uh    + (size_t)flat * A_DIM;
    const float* pp = proj2 + (size_t)b    * A_DIM;

    float acc0 = 0.0f, acc1 = 0.0f;
#pragma unroll
    for (int c = 0; c < 4; ++c) {
        const int off = c * 256 + lane * 4;
        float4 u = *(const float4*)(up + off);
        float4 p = *(const float4*)(pp + off);
        float4 w = *(const float4*)(w_a1 + off);
        float e0 = __builtin_amdgcn_exp2f(fmaf(u.x, KC, p.x));
        float e1 = __builtin_amdgcn_exp2f(fmaf(u.y, KC, p.y));
        float e2 = __builtin_amdgcn_exp2f(fmaf(u.z, KC, p.z));
        float e3 = __builtin_amdgcn_exp2f(fmaf(u.w, KC, p.w));
        acc0 = fmaf(w.x, __builtin_amdgcn_rcpf(e0 + 1.0f), acc0);
        acc1 = fmaf(w.y, __builtin_amdgcn_rcpf(e1 + 1.0f), acc1);
        acc0 = fmaf(w.z, __builtin_amdgcn_rcpf(e2 + 1.0f), acc0);
        acc1 = fmaf(w.w, __builtin_amdgcn_rcpf(e3 + 1.0f), acc1);
    }
    float acc = acc0 + acc1;
#pragma unroll
    for (int off = 32; off > 0; off >>= 1)
        acc += __shfl_down(acc, off);
    if (lane == 0)
        e_raw[flat] = __builtin_amdgcn_exp2f(fmaf(acc, -KC, c0p[0])) * mask[flat];
}

// ---------------------------------------------------------------------------
// K3: normalize over L + attend[b][h] = sum_l e[l][b] * xs_h[l][b][h]
// grid (8 h-chunks x 128 b), 256 threads, 1 float/thread -> 4 waves/SIMD.
// ---------------------------------------------------------------------------
__global__ __launch_bounds__(256) void k3_attend(const float* __restrict__ e_raw,
                                                 const float* __restrict__ xs_h,
                                                 float* __restrict__ out_e,
                                                 float* __restrict__ out_att) {
    __shared__ float se[L_DIM];
    __shared__ float s_inv;
    const int b     = blockIdx.y;
    const int chunk = blockIdx.x;
    const int t     = threadIdx.x;

    if (t < L_DIM) se[t] = e_raw[t * B_DIM + b];
    __syncthreads();
    if (t < 64) {
        float v = se[t] + se[t + 64];
#pragma unroll
        for (int off = 32; off > 0; off >>= 1)
            v += __shfl_down(v, off);
        if (t == 0) s_inv = 1.0f / v;
    }
    __syncthreads();
    if (t < L_DIM) se[t] *= s_inv;
    __syncthreads();
    if (chunk == 0 && t < L_DIM) out_e[t * B_DIM + b] = se[t];

    const int h0 = chunk * 256 + t;
    const float* xp = xs_h + (size_t)b * H_DIM + h0;
    float a0 = 0.0f, a1 = 0.0f;
#pragma unroll 8
    for (int l = 0; l < L_DIM; l += 2) {
        a0 = fmaf(se[l],     xp[(size_t)l       * (B_DIM * H_DIM)], a0);
        a1 = fmaf(se[l + 1], xp[(size_t)(l + 1) * (B_DIM * H_DIM)], a1);
    }
    out_att[(size_t)b * H_DIM + h0] = a0 + a1;
}

// ---------------------------------------------------------------------------
extern "C" void kernel_launch(void* const* d_in, const int* in_sizes, int n_in,
                              void* d_out, int out_size, void* d_ws, size_t ws_size,
                              hipStream_t stream) {
    const float* s_tm1 = (const float*)d_in[0];  // (B, D)
    const float* xs_h  = (const float*)d_in[1];  // (L, B, H)
    const float* uh    = (const float*)d_in[2];  // (L, B, A)
    const float* mask  = (const float*)d_in[3];  // (L, B)
    const float* W_sa  = (const float*)d_in[4];  // (A, D)
    const float* b_sa  = (const float*)d_in[5];  // (A,)
    const float* w_a1  = (const float*)d_in[6];  // (A,)
    const float* b_a1  = (const float*)d_in[7];  // scalar

    float* proj_part = (float*)d_ws;                                // 16*B*A floats (8 MB)
    float* proj2     = proj_part + (size_t)KSPLIT * B_DIM * A_DIM;  // B*A floats
    float* e_raw     = proj2 + (size_t)B_DIM * A_DIM;               // L*B floats
    float* c0        = e_raw + (size_t)L_DIM * B_DIM;               // 1 float

    float* out_e   = (float*)d_out;                   // (L, B)
    float* out_att = out_e + L_DIM * B_DIM;           // (B, H)

    k1_gemm_part<<<dim3(A_DIM / 64, B_DIM / 64, KSPLIT), 256, 0, stream>>>(
        s_tm1, W_sa, proj_part);
    k1_reduce<<<dim3(B_DIM * A_DIM / 4 / 256), 256, 0, stream>>>(
        proj_part, b_sa, w_a1, b_a1, proj2, c0);
    k2_logits<<<dim3(L_DIM * B_DIM / 4), 256, 0, stream>>>(uh, proj2, w_a1,
                                                           c0, mask, e_raw);
    k3_attend<<<dim3(H_DIM / 256, B_DIM), 256, 0, stream>>>(e_raw, xs_h,
                                                            out_e, out_att);
}